// Round 1
// baseline (900.690 us; speedup 1.0000x reference)
//
#include <hip/hip_runtime.h>
#include <cstdint>
#include <cstddef>

#define B_ 2
#define N_ 2048
#define D_ 64
#define A_ 16
#define E_ 2
#define T_ 5
#define H_ 128

// ---------------------------------------------------------------------------
// transform: ins[b,e,n,:] = h[b,n,:] @ W_in[e] + b_in[e]   (dir=0)
//            outs[b,e,n,:] = h[b,n,:] @ W_out[e] + b_out[e] (dir=1)
// grid: (N/4, B*E*2), block 256 (4 nodes x 64 lanes)
// ---------------------------------------------------------------------------
__global__ void transform_kernel(const float* __restrict__ h,
                                 const float* __restrict__ W_in, const float* __restrict__ b_in,
                                 const float* __restrict__ W_out, const float* __restrict__ b_out,
                                 float* __restrict__ ins, float* __restrict__ outs) {
    int y = blockIdx.y;            // bit0=dir, bit1=e, bit2=b
    int dir = y & 1, e = (y >> 1) & 1, b = y >> 2;
    const float* W    = (dir ? W_out : W_in) + e * D_ * D_;
    const float* bias = (dir ? b_out : b_in) + e * D_;
    float* dst = (dir ? outs : ins) + ((size_t)(b * E_ + e)) * N_ * D_;

    __shared__ float Ws[D_ * D_];
    __shared__ float hs[4][D_];
    int tid = threadIdx.x;
    #pragma unroll
    for (int i = 0; i < (D_ * D_) / 256; ++i) Ws[tid + i * 256] = W[tid + i * 256];
    int grp = tid >> 6, d = tid & 63;
    int n = blockIdx.x * 4 + grp;
    hs[grp][d] = h[((size_t)b * N_ + n) * D_ + d];
    __syncthreads();

    float acc = bias[d];
    #pragma unroll
    for (int k = 0; k < D_; ++k) acc = fmaf(hs[grp][k], Ws[k * D_ + d], acc);
    dst[(size_t)n * D_ + d] = acc;
}

// ---------------------------------------------------------------------------
// aggregate: C[b,dir] (N x D) = A[b,dir] (N x E*N) @ V[b,dir] (E*N x D)
// split-K over 4 chunks of 1024; 64x64 output tile per block; atomicAdd epilogue
// grid: (32, B*2, 4), block 256
// ---------------------------------------------------------------------------
__global__ void aggregate_kernel(const float* __restrict__ adj,
                                 const float* __restrict__ ins,
                                 const float* __restrict__ outs,
                                 float* __restrict__ a_in, float* __restrict__ a_out) {
    const int LDA = 2 * N_ * E_;   // 8192
    int bd = blockIdx.y;
    int b = bd >> 1, dir = bd & 1;
    int z = blockIdx.z;
    const float* Arow = adj + ((size_t)b * N_) * LDA + (size_t)dir * (N_ * E_);
    const float* V    = (dir ? outs : ins) + (size_t)b * (E_ * N_) * D_;
    float* C          = (dir ? a_out : a_in) + (size_t)b * N_ * D_;

    int n0 = blockIdx.x * 64;
    int kbase = z * 1024;

    __shared__ float As[64][33];
    __shared__ float Vs[32][65];

    int tid = threadIdx.x;
    int tx = tid & 15, ty = tid >> 4;
    float acc[4][4] = {};

    for (int k0 = 0; k0 < 1024; k0 += 32) {
        #pragma unroll
        for (int i = 0; i < 8; ++i) {
            int idx = tid + i * 256;
            int r = idx >> 5, k = idx & 31;
            As[r][k] = Arow[(size_t)(n0 + r) * LDA + kbase + k0 + k];
        }
        #pragma unroll
        for (int i = 0; i < 8; ++i) {
            int idx = tid + i * 256;
            int kk = idx >> 6, c = idx & 63;
            Vs[kk][c] = V[(size_t)(kbase + k0 + kk) * D_ + c];
        }
        __syncthreads();
        #pragma unroll
        for (int kk = 0; kk < 32; ++kk) {
            float av[4], bv[4];
            #pragma unroll
            for (int i = 0; i < 4; ++i) av[i] = As[ty * 4 + i][kk];
            #pragma unroll
            for (int j = 0; j < 4; ++j) bv[j] = Vs[kk][tx * 4 + j];
            #pragma unroll
            for (int i = 0; i < 4; ++i)
                #pragma unroll
                for (int j = 0; j < 4; ++j) acc[i][j] = fmaf(av[i], bv[j], acc[i][j]);
        }
        __syncthreads();
    }
    #pragma unroll
    for (int i = 0; i < 4; ++i) {
        int r = n0 + ty * 4 + i;
        #pragma unroll
        for (int j = 0; j < 4; ++j)
            atomicAdd(&C[(size_t)r * D_ + tx * 4 + j], acc[i][j]);
    }
}

// ---------------------------------------------------------------------------
// gru: per-node gate update.  grid: B*N/4 blocks, 256 threads (4 nodes x 64)
// ---------------------------------------------------------------------------
__global__ void gru_kernel(float* __restrict__ h,
                           const float* __restrict__ a_in, const float* __restrict__ a_out,
                           const float* __restrict__ Wr, const float* __restrict__ br,
                           const float* __restrict__ Wz, const float* __restrict__ bz,
                           const float* __restrict__ Wh, const float* __restrict__ bh) {
    int tid = threadIdx.x;
    int grp = tid >> 6, d = tid & 63;
    int g = blockIdx.x * 4 + grp;     // 0..B*N-1

    __shared__ float sa[4][3][64];    // [node][ain/aout/h-or-rh][d]
    float ain_d  = a_in[(size_t)g * 64 + d];
    float aout_d = a_out[(size_t)g * 64 + d];
    float h_d    = h[(size_t)g * 64 + d];
    sa[grp][0][d] = ain_d;
    sa[grp][1][d] = aout_d;
    sa[grp][2][d] = h_d;
    __syncthreads();

    float accr = br[d], accz = bz[d];
    #pragma unroll 8
    for (int k = 0; k < 64; ++k) {
        float a0 = sa[grp][0][k], a1 = sa[grp][1][k], a2 = sa[grp][2][k];
        accr = fmaf(a0, Wr[k * 64 + d], accr);
        accr = fmaf(a1, Wr[(64 + k) * 64 + d], accr);
        accr = fmaf(a2, Wr[(128 + k) * 64 + d], accr);
        accz = fmaf(a0, Wz[k * 64 + d], accz);
        accz = fmaf(a1, Wz[(64 + k) * 64 + d], accz);
        accz = fmaf(a2, Wz[(128 + k) * 64 + d], accz);
    }
    float r = 1.0f / (1.0f + expf(-accr));
    float z = 1.0f / (1.0f + expf(-accz));

    __syncthreads();
    sa[grp][2][d] = r * h_d;          // rh replaces h slot
    __syncthreads();

    float acch = bh[d];
    #pragma unroll 8
    for (int k = 0; k < 64; ++k) {
        float a0 = sa[grp][0][k], a1 = sa[grp][1][k], a2 = sa[grp][2][k];
        acch = fmaf(a0, Wh[k * 64 + d], acch);
        acch = fmaf(a1, Wh[(64 + k) * 64 + d], acch);
        acch = fmaf(a2, Wh[(128 + k) * 64 + d], acch);
    }
    float hh = tanhf(acch);
    h[(size_t)g * 64 + d] = (1.0f - z) * h_d + z * hh;
}

// ---------------------------------------------------------------------------
// output: out[b,n] = sum( sigmoid([h,ann] @ Wo1 + bo1) @ Wo2 + bo2 )
// grid: B*N/2 blocks, 256 threads (2 nodes x 128)
// ---------------------------------------------------------------------------
__global__ void output_kernel(const float* __restrict__ h, const float* __restrict__ ann,
                              const float* __restrict__ Wo1, const float* __restrict__ bo1,
                              const float* __restrict__ Wo2, const float* __restrict__ bo2,
                              float* __restrict__ out) {
    int tid = threadIdx.x;
    int grp = tid >> 7, j = tid & 127;
    int g = blockIdx.x * 2 + grp;     // 0..B*N-1

    __shared__ float sx[2][80];
    __shared__ float sy[2][128];
    if (j < 64)       sx[grp][j] = h[(size_t)g * 64 + j];
    else if (j < 80)  sx[grp][j] = ann[(size_t)g * 16 + (j - 64)];
    __syncthreads();

    float acc = bo1[j];
    #pragma unroll
    for (int i = 0; i < 80; ++i) acc = fmaf(sx[grp][i], Wo1[i * 128 + j], acc);
    float y = 1.0f / (1.0f + expf(-acc));
    sy[grp][j] = y * Wo2[j];
    __syncthreads();

    if (j == 0) {
        float s = bo2[0];
        #pragma unroll
        for (int k = 0; k < 128; ++k) s += sy[grp][k];
        out[g] = s;
    }
}

// ---------------------------------------------------------------------------
extern "C" void kernel_launch(void* const* d_in, const int* in_sizes, int n_in,
                              void* d_out, int out_size, void* d_ws, size_t ws_size,
                              hipStream_t stream) {
    const float* prop = (const float*)d_in[0];
    const float* ann  = (const float*)d_in[1];
    const float* adj  = (const float*)d_in[2];
    const float* W_in = (const float*)d_in[3];
    const float* b_in = (const float*)d_in[4];
    const float* W_out= (const float*)d_in[5];
    const float* b_out= (const float*)d_in[6];
    const float* Wr   = (const float*)d_in[7];
    const float* br   = (const float*)d_in[8];
    const float* Wz   = (const float*)d_in[9];
    const float* bz   = (const float*)d_in[10];
    const float* Wh   = (const float*)d_in[11];
    const float* bh   = (const float*)d_in[12];
    const float* Wo1  = (const float*)d_in[13];
    const float* bo1  = (const float*)d_in[14];
    const float* Wo2  = (const float*)d_in[15];
    const float* bo2  = (const float*)d_in[16];
    float* out = (float*)d_out;

    char* ws = (char*)d_ws;
    float* h     = (float*)(ws);                    // 1 MB
    float* ins   = (float*)(ws + 1 * (1 << 20));    // 2 MB
    float* outs  = (float*)(ws + 3 * (1 << 20));    // 2 MB
    float* a_in  = (float*)(ws + 5 * (1 << 20));    // 1 MB
    float* a_out = (float*)(ws + 6 * (1 << 20));    // 1 MB (contiguous after a_in)

    hipMemcpyAsync(h, prop, (size_t)B_ * N_ * D_ * sizeof(float),
                   hipMemcpyDeviceToDevice, stream);

    for (int t = 0; t < T_; ++t) {
        transform_kernel<<<dim3(N_ / 4, B_ * E_ * 2), 256, 0, stream>>>(
            h, W_in, b_in, W_out, b_out, ins, outs);
        hipMemsetAsync(a_in, 0, 2 * (1 << 20), stream);
        aggregate_kernel<<<dim3(N_ / 64, B_ * 2, 4), 256, 0, stream>>>(
            adj, ins, outs, a_in, a_out);
        gru_kernel<<<dim3(B_ * N_ / 4), 256, 0, stream>>>(
            h, a_in, a_out, Wr, br, Wz, bz, Wh, bh);
    }
    output_kernel<<<dim3(B_ * N_ / 2), 256, 0, stream>>>(
        h, ann, Wo1, bo1, Wo2, bo2, out);
}

// Round 2
// 481.453 us; speedup vs baseline: 1.8708x; 1.8708x over previous
//
#include <hip/hip_runtime.h>
#include <cstdint>
#include <cstddef>

#define B_ 2
#define N_ 2048
#define D_ 64
#define E_ 2
#define T_ 5

typedef short bf16x8 __attribute__((ext_vector_type(8)));
typedef unsigned short u16x8 __attribute__((ext_vector_type(8)));
typedef float f32x16 __attribute__((ext_vector_type(16)));

__device__ __forceinline__ unsigned short f2bf(float f) {
    unsigned int x = __float_as_uint(f);
    x += 0x7FFFu + ((x >> 16) & 1u);
    return (unsigned short)(x >> 16);
}

// ---------------------------------------------------------------------------
// convert: adj fp32 (B,N,2*N*E) -> bf16 in MFMA-fragment-tile order.
// Abf[bd][rt][kt][lane][8]: lane&31 = row-in-tile, lane>>5 = k-half, 8 contig k.
// grid (64 rt, 4 bd), 256 threads.
// ---------------------------------------------------------------------------
__global__ void convert_kernel(const float* __restrict__ adj, u16x8* __restrict__ Abf) {
    int rt = blockIdx.x, bd = blockIdx.y;
    int b = bd >> 1, dir = bd & 1;
    int tid = threadIdx.x;
    int lane = tid & 63;
    int row = rt * 32 + (lane & 31);
    int khalf = lane >> 5;
    const float* src = adj + ((size_t)(b * N_ + row)) * (2 * N_ * E_) + dir * (N_ * E_) + khalf * 8;
    u16x8* dst = Abf + ((size_t)(bd * 64 + rt) * 256) * 64 + lane;
    int kt0 = tid >> 6;
    #pragma unroll 4
    for (int i = 0; i < 64; ++i) {
        int kt = kt0 + 4 * i;
        const float* s = src + kt * 16;
        float4 f0 = *(const float4*)(s);
        float4 f1 = *(const float4*)(s + 4);
        u16x8 o;
        o[0] = f2bf(f0.x); o[1] = f2bf(f0.y); o[2] = f2bf(f0.z); o[3] = f2bf(f0.w);
        o[4] = f2bf(f1.x); o[5] = f2bf(f1.y); o[6] = f2bf(f1.z); o[7] = f2bf(f1.w);
        dst[(size_t)kt * 64] = o;
    }
}

// ---------------------------------------------------------------------------
// transform: V = h @ W + b per (b,dir,e); emits V^T bf16 in fragment order:
// VT[bd][ktg][sub][lane][8]: node k = ktg*16+(lane>>5)*8+j, col d = sub*32+(lane&31)
// grid (32 n-tiles, 8 = b*4+dir*2+e... y: e=y&1, dir=(y>>1)&1, b=y>>2), 256 thr
// ---------------------------------------------------------------------------
__global__ void transform_kernel(const float* __restrict__ h,
                                 const float* __restrict__ W_in, const float* __restrict__ b_in,
                                 const float* __restrict__ W_out, const float* __restrict__ b_out,
                                 u16x8* __restrict__ VT) {
    int y = blockIdx.y;
    int e = y & 1, dir = (y >> 1) & 1, b = y >> 2;
    int bd = y >> 1;                       // b*2 + dir
    const float* W = (dir ? W_out : W_in) + e * D_ * D_;
    const float* bias = (dir ? b_out : b_in) + e * D_;
    int n0 = blockIdx.x * 64;

    __shared__ float hs[64][65];
    __shared__ float Ws[64][64];
    __shared__ float os[64][65];

    int tid = threadIdx.x;
    #pragma unroll
    for (int i = 0; i < 16; ++i) {
        int idx = tid + 256 * i;
        int r = idx >> 6, c = idx & 63;
        hs[r][c] = h[((size_t)(b * N_ + n0 + r)) * D_ + c];
        Ws[r][c] = W[idx];
    }
    __syncthreads();

    int g = tid >> 6, l = tid & 63;
    float acc[16];
    #pragma unroll
    for (int j = 0; j < 16; ++j) acc[j] = bias[g * 16 + j];
    for (int k = 0; k < 64; ++k) {
        float hv = hs[l][k];
        #pragma unroll
        for (int j = 0; j < 16; ++j) acc[j] = fmaf(hv, Ws[k][g * 16 + j], acc[j]);
    }
    #pragma unroll
    for (int j = 0; j < 16; ++j) os[l][g * 16 + j] = acc[j];
    __syncthreads();

    #pragma unroll
    for (int c = 0; c < 2; ++c) {
        int chunk = tid + 256 * c;
        int kt_local = chunk >> 7;
        int sub = (chunk >> 6) & 1;
        int ln = chunk & 63;
        int d = sub * 32 + (ln & 31);
        int nbase = kt_local * 16 + (ln >> 5) * 8;
        u16x8 o;
        #pragma unroll
        for (int j = 0; j < 8; ++j) o[j] = f2bf(os[nbase + j][d]);
        int ktg = e * 128 + blockIdx.x * 4 + kt_local;
        VT[((size_t)bd * 512 + ktg * 2 + sub) * 64 + ln] = o;
    }
}

// ---------------------------------------------------------------------------
// aggregate: apart[split][bd] (2048x64) += A_bf16 @ V_bf16 via MFMA.
// No LDS, no barriers: frags loaded global->VGPR (coalesced by layout).
// grid (8 rowblocks, 4 bd, 8 splits), 512 threads = 8 waves; wave = 32 rows.
// ---------------------------------------------------------------------------
__global__ void __launch_bounds__(512, 2) aggregate_kernel(
        const bf16x8* __restrict__ Abf, const bf16x8* __restrict__ VT,
        float* __restrict__ apart) {
    int bx = blockIdx.x;
    int bd = blockIdx.y;
    int sp = blockIdx.z;
    int tid = threadIdx.x;
    int w = tid >> 6, lane = tid & 63;
    int rt = bx * 8 + w;
    int kt0 = sp * 32;

    const bf16x8* Ap = Abf + ((size_t)(bd * 64 + rt) * 256 + kt0) * 64 + lane;
    const bf16x8* Vp = VT + (size_t)bd * 32768 + (size_t)kt0 * 128 + lane;

    f32x16 acc0 = {}, acc1 = {};
    #pragma unroll 4
    for (int kk = 0; kk < 32; ++kk) {
        bf16x8 a  = Ap[(size_t)kk * 64];
        bf16x8 b0 = Vp[(size_t)kk * 128];
        bf16x8 b1 = Vp[(size_t)kk * 128 + 64];
        acc0 = __builtin_amdgcn_mfma_f32_32x32x16_bf16(a, b0, acc0, 0, 0, 0);
        acc1 = __builtin_amdgcn_mfma_f32_32x32x16_bf16(a, b1, acc1, 0, 0, 0);
    }

    float* Cp = apart + ((size_t)(sp * 4 + bd) * 2048) * 64;
    int col = lane & 31;
    int rbase = rt * 32 + 4 * (lane >> 5);
    #pragma unroll
    for (int reg = 0; reg < 16; ++reg) {
        int row = rbase + (reg & 3) + 8 * (reg >> 2);
        Cp[(size_t)row * 64 + col]      = acc0[reg];
        Cp[(size_t)row * 64 + col + 32] = acc1[reg];
    }
}

// ---------------------------------------------------------------------------
// gru: sums split partials, then gate update. grid B*N/16, 1024 threads.
// ---------------------------------------------------------------------------
__global__ void gru_kernel(float* __restrict__ h,
                           const float* __restrict__ apart,
                           const float* __restrict__ Wr, const float* __restrict__ br,
                           const float* __restrict__ Wz, const float* __restrict__ bz,
                           const float* __restrict__ Wh, const float* __restrict__ bh) {
    int tid = threadIdx.x;
    int grp = tid >> 6, d = tid & 63;
    int g = blockIdx.x * 16 + grp;
    int b = g >> 11, n = g & 2047;

    __shared__ float sa[16][3][64];
    float ain = 0.f, aout = 0.f;
    #pragma unroll
    for (int s = 0; s < 8; ++s) {
        ain  += apart[(((size_t)(s * 4 + b * 2    )) * 2048 + n) * 64 + d];
        aout += apart[(((size_t)(s * 4 + b * 2 + 1)) * 2048 + n) * 64 + d];
    }
    float h_d = h[(size_t)g * 64 + d];
    sa[grp][0][d] = ain;
    sa[grp][1][d] = aout;
    sa[grp][2][d] = h_d;
    __syncthreads();

    float accr = br[d], accz = bz[d];
    #pragma unroll 8
    for (int k = 0; k < 64; ++k) {
        float a0 = sa[grp][0][k], a1 = sa[grp][1][k], a2 = sa[grp][2][k];
        accr = fmaf(a0, Wr[k * 64 + d], accr);
        accr = fmaf(a1, Wr[(64 + k) * 64 + d], accr);
        accr = fmaf(a2, Wr[(128 + k) * 64 + d], accr);
        accz = fmaf(a0, Wz[k * 64 + d], accz);
        accz = fmaf(a1, Wz[(64 + k) * 64 + d], accz);
        accz = fmaf(a2, Wz[(128 + k) * 64 + d], accz);
    }
    float r = 1.0f / (1.0f + expf(-accr));
    float z = 1.0f / (1.0f + expf(-accz));

    __syncthreads();
    sa[grp][2][d] = r * h_d;
    __syncthreads();

    float acch = bh[d];
    #pragma unroll 8
    for (int k = 0; k < 64; ++k) {
        float a0 = sa[grp][0][k], a1 = sa[grp][1][k], a2 = sa[grp][2][k];
        acch = fmaf(a0, Wh[k * 64 + d], acch);
        acch = fmaf(a1, Wh[(64 + k) * 64 + d], acch);
        acch = fmaf(a2, Wh[(128 + k) * 64 + d], acch);
    }
    float hh = tanhf(acch);
    h[(size_t)g * 64 + d] = (1.0f - z) * h_d + z * hh;
}

// ---------------------------------------------------------------------------
// output: out[b,n] = sum( sigmoid([h,ann]@Wo1+bo1) @ Wo2 + bo2 )
// ---------------------------------------------------------------------------
__global__ void output_kernel(const float* __restrict__ h, const float* __restrict__ ann,
                              const float* __restrict__ Wo1, const float* __restrict__ bo1,
                              const float* __restrict__ Wo2, const float* __restrict__ bo2,
                              float* __restrict__ out) {
    int tid = threadIdx.x;
    int grp = tid >> 7, j = tid & 127;
    int g = blockIdx.x * 2 + grp;

    __shared__ float sx[2][80];
    __shared__ float sy[2][128];
    if (j < 64)       sx[grp][j] = h[(size_t)g * 64 + j];
    else if (j < 80)  sx[grp][j] = ann[(size_t)g * 16 + (j - 64)];
    __syncthreads();

    float acc = bo1[j];
    #pragma unroll
    for (int i = 0; i < 80; ++i) acc = fmaf(sx[grp][i], Wo1[i * 128 + j], acc);
    float y = 1.0f / (1.0f + expf(-acc));
    sy[grp][j] = y * Wo2[j];
    __syncthreads();

    if (j == 0) {
        float s = bo2[0];
        #pragma unroll
        for (int k = 0; k < 128; ++k) s += sy[grp][k];
        out[g] = s;
    }
}

// ---------------------------------------------------------------------------
extern "C" void kernel_launch(void* const* d_in, const int* in_sizes, int n_in,
                              void* d_out, int out_size, void* d_ws, size_t ws_size,
                              hipStream_t stream) {
    const float* prop = (const float*)d_in[0];
    const float* ann  = (const float*)d_in[1];
    const float* adj  = (const float*)d_in[2];
    const float* W_in = (const float*)d_in[3];
    const float* b_in = (const float*)d_in[4];
    const float* W_out= (const float*)d_in[5];
    const float* b_out= (const float*)d_in[6];
    const float* Wr   = (const float*)d_in[7];
    const float* br   = (const float*)d_in[8];
    const float* Wz   = (const float*)d_in[9];
    const float* bz   = (const float*)d_in[10];
    const float* Wh   = (const float*)d_in[11];
    const float* bh   = (const float*)d_in[12];
    const float* Wo1  = (const float*)d_in[13];
    const float* bo1  = (const float*)d_in[14];
    const float* Wo2  = (const float*)d_in[15];
    const float* bo2  = (const float*)d_in[16];
    float* out = (float*)d_out;

    char* ws = (char*)d_ws;
    u16x8* Abf   = (u16x8*)ws;                      // 64 MiB
    u16x8* VT    = (u16x8*)(ws + (64ull << 20));    // 2 MiB
    float* apart = (float*)(ws + (66ull << 20));    // 16 MiB
    float* h     = (float*)(ws + (82ull << 20));    // 1 MiB

    convert_kernel<<<dim3(64, 4), 256, 0, stream>>>(adj, Abf);
    hipMemcpyAsync(h, prop, (size_t)B_ * N_ * D_ * sizeof(float),
                   hipMemcpyDeviceToDevice, stream);

    for (int t = 0; t < T_; ++t) {
        transform_kernel<<<dim3(32, 8), 256, 0, stream>>>(
            h, W_in, b_in, W_out, b_out, VT);
        aggregate_kernel<<<dim3(8, 4, 8), 512, 0, stream>>>(
            (const bf16x8*)Abf, (const bf16x8*)VT, apart);
        gru_kernel<<<dim3(B_ * N_ / 16), 1024, 0, stream>>>(
            h, apart, Wr, br, Wz, bz, Wh, bh);
    }
    output_kernel<<<dim3(B_ * N_ / 2), 256, 0, stream>>>(
        h, ann, Wo1, bo1, Wo2, bo2, out);
}